// Round 6
// baseline (493.889 us; speedup 1.0000x reference)
//
#include <hip/hip_runtime.h>

#define LQ     22500
#define SPA_H  58
#define SPA_W  100
#define S_TOT  5800
#define NCAMS  6
#define CDIM   256
#define NB_VAL 544   // ceil(34800/64)
#define NB_Q   352   // ceil(22500/64)
#define NB_VIS 88    // ceil(22500/256)
#define NB_OUT 352   // ceil(22500/64)
#define QB     24    // queries per sampler block
#define NB_SMP 938   // ceil(22500/24) -> <=4 blocks/CU, whole grid co-resident

typedef __attribute__((ext_vector_type(8))) _Float16 half8;
typedef __attribute__((ext_vector_type(4))) _Float16 half4;
typedef __attribute__((ext_vector_type(4))) float f32x4;
typedef __attribute__((ext_vector_type(2))) float f32x2;

__device__ __forceinline__ half8 cvt_f32x8(const float* p) {
  f32x4 a = *(const f32x4*)p;
  f32x4 b = *(const f32x4*)(p + 4);
  half8 r;
  r[0] = (_Float16)a.x; r[1] = (_Float16)a.y; r[2] = (_Float16)a.z; r[3] = (_Float16)a.w;
  r[4] = (_Float16)b.x; r[5] = (_Float16)b.y; r[6] = (_Float16)b.z; r[7] = (_Float16)b.w;
  return r;
}

// C[M x N] = A[M x 256] @ W[N x 256]^T + bias.  64-row M-tile (measured-fast
// r3 geometry), 4 waves own disjoint column ranges, B-fragments reused across
// 4 row-tiles.  W f32 with inline f16 cvt.  A_F16: A is f16 else f32.
// BSEL=1: W/bias split at col 128 (W_off ++ W_attn).
// OUT_MODE: 0 = f32 out; 2 = f16 out; 3 = query special: cols<128 ->
//   pre-scaled f16 offsets to outA, cols>=128 -> per-head-octet softmax
//   (8-lane shfl_xor) -> f32 outB.
template<int N, int OUT_MODE, int BSEL, bool A_F16>
__device__ __forceinline__ void gemm_body(
    const void* __restrict__ Av, const float* __restrict__ W0,
    const float* __restrict__ W1, const float* __restrict__ b0,
    const float* __restrict__ b1, void* __restrict__ outA,
    float* __restrict__ outB, int M, int bid)
{
  constexpr int K  = CDIM;
  constexpr int NT = (N / 4) / 16;
  const int lane = threadIdx.x & 63;
  const int wave = threadIdx.x >> 6;
  const int m15  = lane & 15;
  const int quad = lane >> 4;
  const int rowbase = bid * 64;
  const int colbase = wave * (N / 4);

  const float* wp[NT];
  float bv[NT];
#pragma unroll
  for (int t = 0; t < NT; ++t) {
    const int c = colbase + t * 16 + m15;
    if (BSEL == 0) { wp[t] = W0 + (size_t)c * K; bv[t] = b0[c]; }
    else {
      wp[t] = (c < 128) ? (W0 + (size_t)c * K) : (W1 + (size_t)(c - 128) * K);
      bv[t] = (c < 128) ? b0[c] : b1[c - 128];
    }
  }

  f32x4 acc[4][NT];
#pragma unroll
  for (int rt = 0; rt < 4; ++rt)
#pragma unroll
    for (int t = 0; t < NT; ++t) acc[rt][t] = (f32x4){0.f, 0.f, 0.f, 0.f};

#pragma unroll
  for (int kk = 0; kk < K; kk += 32) {
    const int ko = kk + quad * 8;
    half8 a[4], b[NT];
#pragma unroll
    for (int rt = 0; rt < 4; ++rt) {
      int row = rowbase + rt * 16 + m15;
      row = row < M ? row : M - 1;
      if (A_F16) a[rt] = *(const half8*)((const _Float16*)Av + (size_t)row * K + ko);
      else       a[rt] = cvt_f32x8((const float*)Av + (size_t)row * K + ko);
    }
#pragma unroll
    for (int t = 0; t < NT; ++t) b[t] = cvt_f32x8(wp[t] + ko);
#pragma unroll
    for (int t = 0; t < NT; ++t)
#pragma unroll
      for (int rt = 0; rt < 4; ++rt)
        acc[rt][t] = __builtin_amdgcn_mfma_f32_16x16x32_f16(a[rt], b[t], acc[rt][t], 0, 0, 0);
  }

#pragma unroll
  for (int rt = 0; rt < 4; ++rt) {
    const int orow = rowbase + rt * 16 + quad * 4;
#pragma unroll
    for (int t = 0; t < NT; ++t) {
      const int col = colbase + t * 16 + m15;
      if (OUT_MODE == 3) {
        if (col >= 128) {
#pragma unroll
          for (int i = 0; i < 4; ++i) {
            const float v = acc[rt][t][i] + bv[t];
            float mx = v;
            mx = fmaxf(mx, __shfl_xor(mx, 1, 64));
            mx = fmaxf(mx, __shfl_xor(mx, 2, 64));
            mx = fmaxf(mx, __shfl_xor(mx, 4, 64));
            const float e = __expf(v - mx);
            float sm = e;
            sm += __shfl_xor(sm, 1, 64);
            sm += __shfl_xor(sm, 2, 64);
            sm += __shfl_xor(sm, 4, 64);
            const int r = orow + i;
            if (r < M) outB[(size_t)r * 64 + (col - 128)] = e / sm;
          }
        } else {
          const float sc = (col & 1) ? (1.f / SPA_H) : (1.f / SPA_W);
#pragma unroll
          for (int i = 0; i < 4; ++i) {
            const int r = orow + i;
            if (r < M)
              ((_Float16*)outA)[(size_t)r * 128 + col] =
                  (_Float16)((acc[rt][t][i] + bv[t]) * sc);
          }
        }
      } else {
#pragma unroll
        for (int i = 0; i < 4; ++i) {
          const int r = orow + i;
          if (r < M) {
            const float v = acc[rt][t][i] + bv[t];
            if (OUT_MODE == 0) ((float*)outA)[(size_t)r * N + col] = v;
            else               ((_Float16*)outA)[(size_t)r * N + col] = (_Float16)v;
          }
        }
      }
    }
  }
}

// per-query visibility bitmask + 1/visible-count
__device__ __forceinline__ void vis_body(const int* __restrict__ bev,
                                         unsigned char* __restrict__ vm,
                                         float* __restrict__ invc, int idx) {
  if (idx >= LQ) return;
  int cnt = 0; unsigned m = 0;
#pragma unroll
  for (int c = 0; c < NCAMS; ++c) {
    const int4 b4 = *(const int4*)(bev + ((size_t)c * LQ + idx) * 4);
    const int v = (b4.x + b4.y + b4.z + b4.w) > 0 ? 1 : 0;
    m |= (unsigned)v << c; cnt += v;
  }
  vm[idx] = (unsigned char)m;
  invc[idx] = 1.f / (float)(cnt > 0 ? cnt : 1);
}

// Fused front-end: [0,544) value GEMM, [544,896) query GEMM (offsets f16 +
// softmaxed weights f32), [896,984) visibility precompute.
__global__ __launch_bounds__(256, 2) void fused_front(
    const float* __restrict__ value, const float* __restrict__ query,
    const int* __restrict__ bev,
    const float* __restrict__ W_val, const float* __restrict__ b_val,
    const float* __restrict__ W_off, const float* __restrict__ b_off,
    const float* __restrict__ W_attn, const float* __restrict__ b_attn,
    _Float16* __restrict__ vp, _Float16* __restrict__ offb,
    float* __restrict__ wbuf, unsigned char* __restrict__ vm,
    float* __restrict__ invc) {
  const int bid = blockIdx.x;
  if (bid < NB_VAL)
    gemm_body<256, 2, 0, false>(value, W_val, nullptr, b_val, nullptr, vp,
                                nullptr, NCAMS * S_TOT, bid);
  else if (bid < NB_VAL + NB_Q)
    gemm_body<192, 3, 1, false>(query, W_off, W_attn, b_off, b_attn, offb,
                                wbuf, LQ, bid - NB_VAL);
  else
    vis_body(bev, vm, invc, (bid - NB_VAL - NB_Q) * 256 + (int)threadIdx.x);
}

// out = slots(f16) @ W_out^T + b_out (invc already folded into slots).
__global__ __launch_bounds__(256, 2) void out_gemm(
    const _Float16* __restrict__ slots, const float* __restrict__ W_out,
    const float* __restrict__ b_out, float* __restrict__ out) {
  gemm_body<256, 0, 0, true>(slots, W_out, nullptr, b_out, nullptr, out,
                             nullptr, LQ, blockIdx.x);
}

// Per-point engine: 4 clamped taps, validity folded into weights, 4 x 16B
// loads batched.  acc accumulates ACROSS cams in registers.
__device__ __forceinline__ void sample_cam(
    float (&acc)[8], const _Float16* __restrict__ vpc,
    const float* __restrict__ sref, const float* __restrict__ soff,
    const float* __restrict__ sw)
{
#pragma unroll
  for (int p = 0; p < 8; ++p) {
    const int z = p & 3;
    const float x = (sref[z * 2 + 0] + soff[p * 2 + 0]) * 100.f - 0.5f;
    const float y = (sref[z * 2 + 1] + soff[p * 2 + 1]) * 58.f - 0.5f;
    const float x0f = floorf(x), y0f = floorf(y);
    const float fx = x - x0f, fy = y - y0f;
    const int x0 = (int)x0f, y0 = (int)y0f;
    const float wgt = sw[p];
    const float gx0 = 1.f - fx, gx1 = fx;
    const float gy0 = (1.f - fy) * wgt, gy1 = fy * wgt;
    const float vx0 = ((unsigned)x0 < SPA_W) ? 1.f : 0.f;
    const float vx1 = ((unsigned)(x0 + 1) < SPA_W) ? 1.f : 0.f;
    const float vy0 = ((unsigned)y0 < SPA_H) ? 1.f : 0.f;
    const float vy1 = ((unsigned)(y0 + 1) < SPA_H) ? 1.f : 0.f;
    const float w00 = gy0 * gx0 * (vy0 * vx0);
    const float w01 = gy0 * gx1 * (vy0 * vx1);
    const float w10 = gy1 * gx0 * (vy1 * vx0);
    const float w11 = gy1 * gx1 * (vy1 * vx1);
    const int x0c = min(max(x0, 0), SPA_W - 1);
    const int x1c = min(max(x0 + 1, 0), SPA_W - 1);
    const int y0c = min(max(y0, 0), SPA_H - 1);
    const int y1c = min(max(y0 + 1, 0), SPA_H - 1);
    const int r0 = y0c * SPA_W, r1 = y1c * SPA_W;
    const half8 a00 = *(const half8*)(vpc + ((size_t)(r0 + x0c) << 8));
    const half8 a01 = *(const half8*)(vpc + ((size_t)(r0 + x1c) << 8));
    const half8 a10 = *(const half8*)(vpc + ((size_t)(r1 + x0c) << 8));
    const half8 a11 = *(const half8*)(vpc + ((size_t)(r1 + x1c) << 8));
#pragma unroll
    for (int i = 0; i < 8; ++i) {
      float v = acc[i];
      v = fmaf(w00, (float)a00[i], v);
      v = fmaf(w01, (float)a01[i], v);
      v = fmaf(w10, (float)a10[i], v);
      v = fmaf(w11, (float)a11[i], v);
      acc[i] = v;
    }
  }
}

// Single-launch sampler.  938 blocks x 24 queries: whole grid co-resident
// (<=4 blocks/CU), so all blocks sweep cams in near-lockstep -> instantaneous
// L2 working set ~ one 2.97 MB cam slice (the r2 thrash came from random cam
// phases).  Cam loop OUTER, register accumulation across cams -> no global
// RMW, no races, one launch, one staging of offb/wbuf.
// Thread: ql=t>>5 (octet-local query), s=t&31, h=s>>2, quad=s&3.
__global__ __launch_bounds__(256, 4) void sampler_all(
    const _Float16* __restrict__ vp,     // (6, 5800, 256) f16
    const _Float16* __restrict__ offb,   // (LQ, 128) f16, pre-scaled
    const float* __restrict__ wbuf,      // (LQ, 64) f32, softmaxed
    const float* __restrict__ ref,       // f32 (6, 1, LQ, 4, 2)
    const unsigned char* __restrict__ vm,
    const float* __restrict__ invc,
    _Float16* __restrict__ slots)        // (LQ, 256) f16, invc folded
{
  const int t    = threadIdx.x;
  const int ql   = t >> 5;
  const int s    = t & 31;
  const int h    = s >> 2;
  const int quad = s & 3;
  const int q0   = blockIdx.x * QB;
  const int h8   = h * 8;
  const int chbase = h * 32 + quad * 8;

  __shared__ float s_off[QB][128];      // 12,288 B
  __shared__ float s_w[QB][64];         //  6,144 B
  __shared__ float s_ref[QB][8];        //    768 B
  __shared__ float s_invc[QB];
  __shared__ unsigned char s_vm[QB];

  // one-time staging: offsets, weights, vm, invc for all 24 queries
#pragma unroll
  for (int rep = 0; rep < 3; ++rep) {
    const int idx = t + rep * 256;      // 768 half4-slots: u=idx>>5, g=idx&31
    const int u = idx >> 5, g = idx & 31;
    const int qq = min(q0 + u, LQ - 1);
    const half4 o4 = *(const half4*)(offb + (size_t)qq * 128 + g * 4);
#pragma unroll
    for (int k = 0; k < 4; ++k) s_off[u][g * 4 + k] = (float)o4[k];
  }
#pragma unroll
  for (int rep = 0; rep < 3; ++rep) {
    const int idx = t + rep * 256;      // 768 f32x2-slots
    const int u = idx >> 5, g = idx & 31;
    const int qq = min(q0 + u, LQ - 1);
    const f32x2 w2 = *(const f32x2*)(wbuf + (size_t)qq * 64 + g * 2);
    s_w[u][g * 2] = w2.x;
    s_w[u][g * 2 + 1] = w2.y;
  }
  if (t < QB) {
    const int qq = q0 + t;
    s_vm[t]   = (qq < LQ) ? vm[qq] : (unsigned char)0;
    s_invc[t] = (qq < LQ) ? invc[qq] : 1.f;
  }

  float accA[8], accB[8], accC[8];
#pragma unroll
  for (int i = 0; i < 8; ++i) { accA[i] = 0.f; accB[i] = 0.f; accC[i] = 0.f; }

  for (int cam = 0; cam < NCAMS; ++cam) {
    __syncthreads();                    // protect s_ref from previous readers
    if (t < QB * 8) {                   // 192 threads: u=t>>3, k=t&7
      const int u = t >> 3, k = t & 7;
      const int qq = min(q0 + u, LQ - 1);
      s_ref[u][k] = ref[((size_t)cam * LQ + qq) * 8 + k];
    }
    __syncthreads();

    const _Float16* vpc = vp + (size_t)cam * (S_TOT * CDIM) + chbase;
    {
      const int u = ql;                 // octet 0
      if ((s_vm[u] >> cam) & 1)
        sample_cam(accA, vpc, s_ref[u], &s_off[u][h8 * 2], &s_w[u][h8]);
    }
    {
      const int u = 8 + ql;             // octet 1
      if ((s_vm[u] >> cam) & 1)
        sample_cam(accB, vpc, s_ref[u], &s_off[u][h8 * 2], &s_w[u][h8]);
    }
    {
      const int u = 16 + ql;            // octet 2
      if ((s_vm[u] >> cam) & 1)
        sample_cam(accC, vpc, s_ref[u], &s_off[u][h8 * 2], &s_w[u][h8]);
    }
  }

  // final write: f16 slots with invc folded (exactly once per query)
  {
    const int qq = q0 + ql;
    if (qq < LQ) {
      const float sc = s_invc[ql];
      half8 o;
#pragma unroll
      for (int i = 0; i < 8; ++i) o[i] = (_Float16)(accA[i] * sc);
      *(half8*)(slots + (size_t)qq * CDIM + chbase) = o;
    }
  }
  {
    const int qq = q0 + 8 + ql;
    if (qq < LQ) {
      const float sc = s_invc[8 + ql];
      half8 o;
#pragma unroll
      for (int i = 0; i < 8; ++i) o[i] = (_Float16)(accB[i] * sc);
      *(half8*)(slots + (size_t)qq * CDIM + chbase) = o;
    }
  }
  {
    const int qq = q0 + 16 + ql;
    if (qq < LQ) {
      const float sc = s_invc[16 + ql];
      half8 o;
#pragma unroll
      for (int i = 0; i < 8; ++i) o[i] = (_Float16)(accC[i] * sc);
      *(half8*)(slots + (size_t)qq * CDIM + chbase) = o;
    }
  }
}

extern "C" void kernel_launch(void* const* d_in, const int* in_sizes, int n_in,
                              void* d_out, int out_size, void* d_ws, size_t ws_size,
                              hipStream_t stream) {
  const float* query  = (const float*)d_in[0];
  const float* refpts = (const float*)d_in[1];
  const int*   bev    = (const int*)d_in[2];
  const float* value  = (const float*)d_in[3];
  const float* W_off  = (const float*)d_in[4];
  const float* b_off  = (const float*)d_in[5];
  const float* W_attn = (const float*)d_in[6];
  const float* b_attn = (const float*)d_in[7];
  const float* W_val  = (const float*)d_in[8];
  const float* b_val  = (const float*)d_in[9];
  const float* W_out  = (const float*)d_in[10];
  const float* b_out  = (const float*)d_in[11];

  char* ws = (char*)d_ws;
  _Float16*      vp    = (_Float16*)(ws + 0);          // 17,817,600
  _Float16*      offb  = (_Float16*)(ws + 17817600);   //  5,760,000
  float*         wbuf  = (float*)   (ws + 23577600);   //  5,760,000
  unsigned char* vm    = (unsigned char*)(ws + 29337600); // 22,528 (padded)
  float*         invc  = (float*)   (ws + 29360128);   //     90,000
  _Float16*      slots = (_Float16*)(ws + 29450128);   // 11,520,000
                                                       // total: 40,970,128 B

  fused_front<<<NB_VAL + NB_Q + NB_VIS, 256, 0, stream>>>(
      value, query, bev, W_val, b_val, W_off, b_off, W_attn, b_attn,
      vp, offb, wbuf, vm, invc);

  sampler_all<<<NB_SMP, 256, 0, stream>>>(vp, offb, wbuf, refpts, vm, invc, slots);

  out_gemm<<<NB_OUT, 256, 0, stream>>>(slots, W_out, b_out, (float*)d_out);
}

// Round 7
// 415.856 us; speedup vs baseline: 1.1876x; 1.1876x over previous
//
#include <hip/hip_runtime.h>

#define LQ     22500
#define SPA_H  58
#define SPA_W  100
#define S_TOT  5800
#define NCAMS  6
#define CDIM   256
#define NB_VAL 544   // ceil(34800/64)
#define NB_Q   352   // ceil(22500/64)
#define NB_VIS 88    // ceil(22500/256)
#define NB_OUT 352   // ceil(22500/64)

typedef __attribute__((ext_vector_type(8))) _Float16 half8;
typedef __attribute__((ext_vector_type(4))) float f32x4;

__device__ __forceinline__ half8 cvt_f32x8(const float* p) {
  f32x4 a = *(const f32x4*)p;
  f32x4 b = *(const f32x4*)(p + 4);
  half8 r;
  r[0] = (_Float16)a.x; r[1] = (_Float16)a.y; r[2] = (_Float16)a.z; r[3] = (_Float16)a.w;
  r[4] = (_Float16)b.x; r[5] = (_Float16)b.y; r[6] = (_Float16)b.z; r[7] = (_Float16)b.w;
  return r;
}

// C[M x N] = A[M x 256] @ W[N x 256]^T + bias.  64-row M-tile (measured-fast
// geometry, r3: 68 us), 4 waves own disjoint column ranges.  W f32 with
// inline f16 cvt.  A_F16: A is f16 else f32.
// BSEL=1: W/bias split at col 128 (W_off ++ W_attn).
// OUT_MODE: 0 = f32 out; 2 = f16 out; 3 = query special: cols<128 ->
//   pre-scaled f16 offsets to outA, cols>=128 -> per-head-octet softmax
//   (8-lane shfl_xor) -> f32 outB.
template<int N, int OUT_MODE, int BSEL, bool A_F16>
__device__ __forceinline__ void gemm_body(
    const void* __restrict__ Av, const float* __restrict__ W0,
    const float* __restrict__ W1, const float* __restrict__ b0,
    const float* __restrict__ b1, void* __restrict__ outA,
    float* __restrict__ outB, int M, int bid)
{
  constexpr int K  = CDIM;
  constexpr int NT = (N / 4) / 16;
  const int lane = threadIdx.x & 63;
  const int wave = threadIdx.x >> 6;
  const int m15  = lane & 15;
  const int quad = lane >> 4;
  const int rowbase = bid * 64;
  const int colbase = wave * (N / 4);

  const float* wp[NT];
  float bv[NT];
#pragma unroll
  for (int t = 0; t < NT; ++t) {
    const int c = colbase + t * 16 + m15;
    if (BSEL == 0) { wp[t] = W0 + (size_t)c * K; bv[t] = b0[c]; }
    else {
      wp[t] = (c < 128) ? (W0 + (size_t)c * K) : (W1 + (size_t)(c - 128) * K);
      bv[t] = (c < 128) ? b0[c] : b1[c - 128];
    }
  }

  f32x4 acc[4][NT];
#pragma unroll
  for (int rt = 0; rt < 4; ++rt)
#pragma unroll
    for (int t = 0; t < NT; ++t) acc[rt][t] = (f32x4){0.f, 0.f, 0.f, 0.f};

#pragma unroll
  for (int kk = 0; kk < K; kk += 32) {
    const int ko = kk + quad * 8;
    half8 a[4], b[NT];
#pragma unroll
    for (int rt = 0; rt < 4; ++rt) {
      int row = rowbase + rt * 16 + m15;
      row = row < M ? row : M - 1;
      if (A_F16) a[rt] = *(const half8*)((const _Float16*)Av + (size_t)row * K + ko);
      else       a[rt] = cvt_f32x8((const float*)Av + (size_t)row * K + ko);
    }
#pragma unroll
    for (int t = 0; t < NT; ++t) b[t] = cvt_f32x8(wp[t] + ko);
#pragma unroll
    for (int t = 0; t < NT; ++t)
#pragma unroll
      for (int rt = 0; rt < 4; ++rt)
        acc[rt][t] = __builtin_amdgcn_mfma_f32_16x16x32_f16(a[rt], b[t], acc[rt][t], 0, 0, 0);
  }

#pragma unroll
  for (int rt = 0; rt < 4; ++rt) {
    const int orow = rowbase + rt * 16 + quad * 4;
#pragma unroll
    for (int t = 0; t < NT; ++t) {
      const int col = colbase + t * 16 + m15;
      if (OUT_MODE == 3) {
        if (col >= 128) {
#pragma unroll
          for (int i = 0; i < 4; ++i) {
            const float v = acc[rt][t][i] + bv[t];
            float mx = v;
            mx = fmaxf(mx, __shfl_xor(mx, 1, 64));
            mx = fmaxf(mx, __shfl_xor(mx, 2, 64));
            mx = fmaxf(mx, __shfl_xor(mx, 4, 64));
            const float e = __expf(v - mx);
            float sm = e;
            sm += __shfl_xor(sm, 1, 64);
            sm += __shfl_xor(sm, 2, 64);
            sm += __shfl_xor(sm, 4, 64);
            const int r = orow + i;
            if (r < M) outB[(size_t)r * 64 + (col - 128)] = e / sm;
          }
        } else {
          const float sc = (col & 1) ? (1.f / SPA_H) : (1.f / SPA_W);
#pragma unroll
          for (int i = 0; i < 4; ++i) {
            const int r = orow + i;
            if (r < M)
              ((_Float16*)outA)[(size_t)r * 128 + col] =
                  (_Float16)((acc[rt][t][i] + bv[t]) * sc);
          }
        }
      } else {
#pragma unroll
        for (int i = 0; i < 4; ++i) {
          const int r = orow + i;
          if (r < M) {
            const float v = acc[rt][t][i] + bv[t];
            if (OUT_MODE == 0) ((float*)outA)[(size_t)r * N + col] = v;
            else               ((_Float16*)outA)[(size_t)r * N + col] = (_Float16)v;
          }
        }
      }
    }
  }
}

// per-query visibility bitmask + 1/visible-count
__device__ __forceinline__ void vis_body(const int* __restrict__ bev,
                                         unsigned char* __restrict__ vm,
                                         float* __restrict__ invc, int idx) {
  if (idx >= LQ) return;
  int cnt = 0; unsigned m = 0;
#pragma unroll
  for (int c = 0; c < NCAMS; ++c) {
    const int4 b4 = *(const int4*)(bev + ((size_t)c * LQ + idx) * 4);
    const int v = (b4.x + b4.y + b4.z + b4.w) > 0 ? 1 : 0;
    m |= (unsigned)v << c; cnt += v;
  }
  vm[idx] = (unsigned char)m;
  invc[idx] = 1.f / (float)(cnt > 0 ? cnt : 1);
}

// Fused front-end: [0,544) value GEMM, [544,896) query GEMM (offsets f16 +
// softmaxed weights f32), [896,984) visibility precompute.
__global__ __launch_bounds__(256, 2) void fused_front(
    const float* __restrict__ value, const float* __restrict__ query,
    const int* __restrict__ bev,
    const float* __restrict__ W_val, const float* __restrict__ b_val,
    const float* __restrict__ W_off, const float* __restrict__ b_off,
    const float* __restrict__ W_attn, const float* __restrict__ b_attn,
    _Float16* __restrict__ vp, _Float16* __restrict__ offb,
    float* __restrict__ wbuf, unsigned char* __restrict__ vm,
    float* __restrict__ invc) {
  const int bid = blockIdx.x;
  if (bid < NB_VAL)
    gemm_body<256, 2, 0, false>(value, W_val, nullptr, b_val, nullptr, vp,
                                nullptr, NCAMS * S_TOT, bid);
  else if (bid < NB_VAL + NB_Q)
    gemm_body<192, 3, 1, false>(query, W_off, W_attn, b_off, b_attn, offb,
                                wbuf, LQ, bid - NB_VAL);
  else
    vis_body(bev, vm, invc, (bid - NB_VAL - NB_Q) * 256 + (int)threadIdx.x);
}

// out = slots(f16) @ W_out^T + b_out (invc already folded into slots).
__global__ __launch_bounds__(256, 2) void out_gemm(
    const _Float16* __restrict__ slots, const float* __restrict__ W_out,
    const float* __restrict__ b_out, float* __restrict__ out) {
  gemm_body<256, 0, 0, true>(slots, W_out, nullptr, b_out, nullptr, out,
                             nullptr, LQ, blockIdx.x);
}

// Sampler: the r0-baseline memory structure VERBATIM (the only config
// measured at 94 MB HBM fetch / 177 us): 8 queries per 128-thread block,
// 16 lanes/query (ql=t>>4, h=s>>1, hf=s&1, 16 channels/lane), branchy
// OOB row/col skip (no clamped loads), per-cam exec-masked `continue`.
// Deltas vs r0 (non-memory only): softmax + offset scaling precomputed in
// the front GEMM epilogue; per-point offsets/weights hoisted to registers
// (kills the 1.6M LDS bank conflicts); visibility from precomputed bitmask.
__global__ __launch_bounds__(128) void sampler(
    const _Float16* __restrict__ vp,     // (6, 5800, 256) f16
    const _Float16* __restrict__ offb,   // (LQ, 128) f16, pre-scaled
    const float* __restrict__ wbuf,      // (LQ, 64) f32, softmaxed
    const float* __restrict__ ref,       // f32 (6, 1, LQ, 4, 2)
    const unsigned char* __restrict__ vm,
    const float* __restrict__ invc,
    _Float16* __restrict__ slots)        // (LQ, 256) f16, invc folded
{
  const int t  = threadIdx.x;
  const int ql = t >> 4;
  const int s  = t & 15;
  const int h  = s >> 1;
  const int hf = s & 1;
  const int q  = blockIdx.x * 8 + ql;
  const bool qok = q < LQ;
  const int qc = qok ? q : LQ - 1;

  __shared__ float s_off[8][128];
  __shared__ float s_w[8][64];
  __shared__ float s_ref[8][48];
  __shared__ unsigned char s_vm[8];
  __shared__ float s_ic[8];

  {
    const half8 o8 = *(const half8*)(offb + (size_t)qc * 128 + s * 8);
#pragma unroll
    for (int k = 0; k < 8; ++k) s_off[ql][s * 8 + k] = (float)o8[k];
    const f32x4 w4 = *(const f32x4*)(wbuf + (size_t)qc * 64 + s * 4);
#pragma unroll
    for (int k = 0; k < 4; ++k) s_w[ql][s * 4 + k] = w4[k];
#pragma unroll
    for (int rep = 0; rep < 3; ++rep) {
      const int k = s + rep * 16;
      s_ref[ql][k] = ref[((size_t)(k >> 3) * LQ + qc) * 8 + (k & 7)];
    }
    if (s == 0) {
      s_vm[ql] = qok ? vm[q] : (unsigned char)0;
      s_ic[ql] = qok ? invc[q] : 1.f;
    }
  }
  __syncthreads();

  // hoist this head's weights + offsets to registers (once)
  float w8[8], ox[8], oy[8];
#pragma unroll
  for (int p = 0; p < 8; ++p) {
    w8[p] = s_w[ql][h * 8 + p];
    ox[p] = s_off[ql][(h * 8 + p) * 2 + 0];
    oy[p] = s_off[ql][(h * 8 + p) * 2 + 1];
  }

  float acc[16];
#pragma unroll
  for (int i = 0; i < 16; ++i) acc[i] = 0.f;

  const int chbase = h * 32 + hf * 16;
  const unsigned vmq = s_vm[ql];

  for (int cam = 0; cam < NCAMS; ++cam) {
    if (!((vmq >> cam) & 1)) continue;  // exec-masked: no loads for invisible
    const _Float16* vpc = vp + (size_t)cam * (S_TOT * CDIM) + chbase;
#pragma unroll
    for (int p = 0; p < 8; ++p) {
      const int z = p & 3;
      const float lx = s_ref[ql][cam * 8 + z * 2 + 0] + ox[p];
      const float ly = s_ref[ql][cam * 8 + z * 2 + 1] + oy[p];
      const float x = lx * 100.f - 0.5f;
      const float y = ly * 58.f - 0.5f;
      const float x0f = floorf(x), y0f = floorf(y);
      const float fx = x - x0f, fy = y - y0f;
      const int x0 = (int)x0f, y0 = (int)y0f;
      const float wgt = w8[p];
      const float w00 = (1.f - fy) * (1.f - fx) * wgt;
      const float w01 = (1.f - fy) * fx * wgt;
      const float w10 = fy * (1.f - fx) * wgt;
      const float w11 = fy * fx * wgt;
      const bool xv0 = (x0 >= 0) && (x0 < SPA_W);
      const bool xv1 = (x0 + 1 >= 0) && (x0 + 1 < SPA_W);
#pragma unroll
      for (int dy = 0; dy < 2; ++dy) {
        const int yy = y0 + dy;
        if (yy < 0 || yy >= SPA_H) continue;
        const _Float16* rowp = vpc + (size_t)(yy * SPA_W) * CDIM;
        const float wl = dy ? w10 : w00;
        const float wr = dy ? w11 : w01;
        if (xv0) {
          const _Float16* tp = rowp + (size_t)x0 * CDIM;
          half8 v0 = *(const half8*)tp;
          half8 v1 = *(const half8*)(tp + 8);
#pragma unroll
          for (int i = 0; i < 8; ++i) acc[i]     = fmaf(wl, (float)v0[i], acc[i]);
#pragma unroll
          for (int i = 0; i < 8; ++i) acc[8 + i] = fmaf(wl, (float)v1[i], acc[8 + i]);
        }
        if (xv1) {
          const _Float16* tp = rowp + (size_t)(x0 + 1) * CDIM;
          half8 v0 = *(const half8*)tp;
          half8 v1 = *(const half8*)(tp + 8);
#pragma unroll
          for (int i = 0; i < 8; ++i) acc[i]     = fmaf(wr, (float)v0[i], acc[i]);
#pragma unroll
          for (int i = 0; i < 8; ++i) acc[8 + i] = fmaf(wr, (float)v1[i], acc[8 + i]);
        }
      }
    }
  }

  if (qok) {
    const float sc = s_ic[ql];
    half8 o0, o1;
#pragma unroll
    for (int i = 0; i < 8; ++i) {
      o0[i] = (_Float16)(acc[i] * sc);
      o1[i] = (_Float16)(acc[8 + i] * sc);
    }
    _Float16* sp = slots + (size_t)q * CDIM + chbase;
    *(half8*)sp = o0;
    *(half8*)(sp + 8) = o1;
  }
}

extern "C" void kernel_launch(void* const* d_in, const int* in_sizes, int n_in,
                              void* d_out, int out_size, void* d_ws, size_t ws_size,
                              hipStream_t stream) {
  const float* query  = (const float*)d_in[0];
  const float* refpts = (const float*)d_in[1];
  const int*   bev    = (const int*)d_in[2];
  const float* value  = (const float*)d_in[3];
  const float* W_off  = (const float*)d_in[4];
  const float* b_off  = (const float*)d_in[5];
  const float* W_attn = (const float*)d_in[6];
  const float* b_attn = (const float*)d_in[7];
  const float* W_val  = (const float*)d_in[8];
  const float* b_val  = (const float*)d_in[9];
  const float* W_out  = (const float*)d_in[10];
  const float* b_out  = (const float*)d_in[11];

  char* ws = (char*)d_ws;
  _Float16*      vp    = (_Float16*)(ws + 0);          // 17,817,600
  _Float16*      offb  = (_Float16*)(ws + 17817600);   //  5,760,000
  float*         wbuf  = (float*)   (ws + 23577600);   //  5,760,000
  unsigned char* vm    = (unsigned char*)(ws + 29337600); // 22,528 (padded)
  float*         invc  = (float*)   (ws + 29360128);   //     90,000
  _Float16*      slots = (_Float16*)(ws + 29450128);   // 11,520,000
                                                       // total: 40,970,128 B

  fused_front<<<NB_VAL + NB_Q + NB_VIS, 256, 0, stream>>>(
      value, query, bev, W_val, b_val, W_off, b_off, W_attn, b_attn,
      vp, offb, wbuf, vm, invc);

  sampler<<<(LQ + 7) / 8, 128, 0, stream>>>(vp, offb, wbuf, refpts, vm, invc, slots);

  out_gemm<<<NB_OUT, 256, 0, stream>>>(slots, W_out, b_out, (float*)d_out);
}

// Round 8
// 412.177 us; speedup vs baseline: 1.1982x; 1.0089x over previous
//
#include <hip/hip_runtime.h>

#define LQ     22500
#define SPA_H  58
#define SPA_W  100
#define S_TOT  5800
#define NCAMS  6
#define CDIM   256
#define NB_VAL 544   // ceil(34800/64)
#define NB_Q   352   // ceil(22500/64)
#define NB_VIS 88    // ceil(22500/256)
#define NB_CVT 32    // 32*256*8 = 65536 = W_out f16 cvt
#define QPB    16    // queries per sampler block (4 waves x 4q, 16 lanes/q)

typedef __attribute__((ext_vector_type(8))) _Float16 half8;
typedef __attribute__((ext_vector_type(4))) float f32x4;

__device__ __forceinline__ half8 cvt_f32x8(const float* p) {
  f32x4 a = *(const f32x4*)p;
  f32x4 b = *(const f32x4*)(p + 4);
  half8 r;
  r[0] = (_Float16)a.x; r[1] = (_Float16)a.y; r[2] = (_Float16)a.z; r[3] = (_Float16)a.w;
  r[4] = (_Float16)b.x; r[5] = (_Float16)b.y; r[6] = (_Float16)b.z; r[7] = (_Float16)b.w;
  return r;
}

// C[M x N] = A[M x 256] @ W[N x 256]^T + bias.  64-row M-tile (measured-fast
// geometry, r3: 68 us), 4 waves own disjoint column ranges.  W f32 with
// inline f16 cvt.
// BSEL=1: W/bias split at col 128 (W_off ++ W_attn).
// OUT_MODE: 2 = f16 out; 3 = query special: cols<128 -> pre-scaled f16
//   offsets to outA, cols>=128 -> per-head-octet softmax (shfl_xor) -> outB.
template<int N, int OUT_MODE, int BSEL>
__device__ __forceinline__ void gemm_body(
    const float* __restrict__ A, const float* __restrict__ W0,
    const float* __restrict__ W1, const float* __restrict__ b0,
    const float* __restrict__ b1, void* __restrict__ outA,
    float* __restrict__ outB, int M, int bid)
{
  constexpr int K  = CDIM;
  constexpr int NT = (N / 4) / 16;
  const int lane = threadIdx.x & 63;
  const int wave = threadIdx.x >> 6;
  const int m15  = lane & 15;
  const int quad = lane >> 4;
  const int rowbase = bid * 64;
  const int colbase = wave * (N / 4);

  const float* wp[NT];
  float bv[NT];
#pragma unroll
  for (int t = 0; t < NT; ++t) {
    const int c = colbase + t * 16 + m15;
    if (BSEL == 0) { wp[t] = W0 + (size_t)c * K; bv[t] = b0[c]; }
    else {
      wp[t] = (c < 128) ? (W0 + (size_t)c * K) : (W1 + (size_t)(c - 128) * K);
      bv[t] = (c < 128) ? b0[c] : b1[c - 128];
    }
  }

  f32x4 acc[4][NT];
#pragma unroll
  for (int rt = 0; rt < 4; ++rt)
#pragma unroll
    for (int t = 0; t < NT; ++t) acc[rt][t] = (f32x4){0.f, 0.f, 0.f, 0.f};

#pragma unroll
  for (int kk = 0; kk < K; kk += 32) {
    const int ko = kk + quad * 8;
    half8 a[4], b[NT];
#pragma unroll
    for (int rt = 0; rt < 4; ++rt) {
      int row = rowbase + rt * 16 + m15;
      row = row < M ? row : M - 1;
      a[rt] = cvt_f32x8(A + (size_t)row * K + ko);
    }
#pragma unroll
    for (int t = 0; t < NT; ++t) b[t] = cvt_f32x8(wp[t] + ko);
#pragma unroll
    for (int t = 0; t < NT; ++t)
#pragma unroll
      for (int rt = 0; rt < 4; ++rt)
        acc[rt][t] = __builtin_amdgcn_mfma_f32_16x16x32_f16(a[rt], b[t], acc[rt][t], 0, 0, 0);
  }

#pragma unroll
  for (int rt = 0; rt < 4; ++rt) {
    const int orow = rowbase + rt * 16 + quad * 4;
#pragma unroll
    for (int t = 0; t < NT; ++t) {
      const int col = colbase + t * 16 + m15;
      if (OUT_MODE == 3) {
        if (col >= 128) {
#pragma unroll
          for (int i = 0; i < 4; ++i) {
            const float v = acc[rt][t][i] + bv[t];
            float mx = v;
            mx = fmaxf(mx, __shfl_xor(mx, 1, 64));
            mx = fmaxf(mx, __shfl_xor(mx, 2, 64));
            mx = fmaxf(mx, __shfl_xor(mx, 4, 64));
            const float e = __expf(v - mx);
            float sm = e;
            sm += __shfl_xor(sm, 1, 64);
            sm += __shfl_xor(sm, 2, 64);
            sm += __shfl_xor(sm, 4, 64);
            const int r = orow + i;
            if (r < M) outB[(size_t)r * 64 + (col - 128)] = e / sm;
          }
        } else {
          const float sc = (col & 1) ? (1.f / SPA_H) : (1.f / SPA_W);
#pragma unroll
          for (int i = 0; i < 4; ++i) {
            const int r = orow + i;
            if (r < M)
              ((_Float16*)outA)[(size_t)r * 128 + col] =
                  (_Float16)((acc[rt][t][i] + bv[t]) * sc);
          }
        }
      } else {
#pragma unroll
        for (int i = 0; i < 4; ++i) {
          const int r = orow + i;
          if (r < M)
            ((_Float16*)outA)[(size_t)r * N + col] = (_Float16)(acc[rt][t][i] + bv[t]);
        }
      }
    }
  }
}

// per-query visibility bitmask + 1/visible-count
__device__ __forceinline__ void vis_body(const int* __restrict__ bev,
                                         unsigned char* __restrict__ vm,
                                         float* __restrict__ invc, int idx) {
  if (idx >= LQ) return;
  int cnt = 0; unsigned m = 0;
#pragma unroll
  for (int c = 0; c < NCAMS; ++c) {
    const int4 b4 = *(const int4*)(bev + ((size_t)c * LQ + idx) * 4);
    const int v = (b4.x + b4.y + b4.z + b4.w) > 0 ? 1 : 0;
    m |= (unsigned)v << c; cnt += v;
  }
  vm[idx] = (unsigned char)m;
  invc[idx] = 1.f / (float)(cnt > 0 ? cnt : 1);
}

// Fused front-end: [0,544) value GEMM, [544,896) query GEMM (offsets f16 +
// softmaxed weights f32), [896,984) visibility, [984,1016) W_out f32->f16.
__global__ __launch_bounds__(256, 2) void fused_front(
    const float* __restrict__ value, const float* __restrict__ query,
    const int* __restrict__ bev,
    const float* __restrict__ W_val, const float* __restrict__ b_val,
    const float* __restrict__ W_off, const float* __restrict__ b_off,
    const float* __restrict__ W_attn, const float* __restrict__ b_attn,
    const float* __restrict__ W_out,
    _Float16* __restrict__ vp, _Float16* __restrict__ offb,
    float* __restrict__ wbuf, unsigned char* __restrict__ vm,
    float* __restrict__ invc, _Float16* __restrict__ Wo_h) {
  const int bid = blockIdx.x;
  if (bid < NB_VAL)
    gemm_body<256, 2, 0>(value, W_val, nullptr, b_val, nullptr, vp,
                         nullptr, NCAMS * S_TOT, bid);
  else if (bid < NB_VAL + NB_Q)
    gemm_body<192, 3, 1>(query, W_off, W_attn, b_off, b_attn, offb,
                         wbuf, LQ, bid - NB_VAL);
  else if (bid < NB_VAL + NB_Q + NB_VIS)
    vis_body(bev, vm, invc, (bid - NB_VAL - NB_Q) * 256 + (int)threadIdx.x);
  else {
    const int idx = (bid - NB_VAL - NB_Q - NB_VIS) * 2048 + (int)threadIdx.x * 8;
    if (idx + 7 < 65536) *(half8*)(Wo_h + idx) = cvt_f32x8(W_out + idx);
  }
}

// Sampler + fused output GEMM.
// Phase 1 (sampler): the r0/r7 memory structure verbatim per wave (4 q x 16
// lanes, branchy OOB skip, per-cam exec-masked continue) — the only config
// measured in the low-HBM-fetch regime.  16 q per 256-thread block.
// Phase 2 (fused out): slots (16 full rows, f16, invc folded) pass through
// LDS; 4 waves compute 16x256x256 GEMM vs f16 W_out; bias; f32 -> d_out.
// Kills the separate out_gemm launch + the 23 MB slots HBM round-trip; MFMA
// work hides under other blocks' gather stalls.
#define SLOT_LD 280   // f16 row stride: 560 B = 16B-aligned; banks 12*m15%32 -> 2-way (free)
__global__ __launch_bounds__(256, 4) void sampler_out(
    const _Float16* __restrict__ vp,     // (6, 5800, 256) f16
    const _Float16* __restrict__ offb,   // (LQ, 128) f16, pre-scaled
    const float* __restrict__ wbuf,      // (LQ, 64) f32, softmaxed
    const float* __restrict__ ref,       // f32 (6, 1, LQ, 4, 2)
    const unsigned char* __restrict__ vm,
    const float* __restrict__ invc,
    const _Float16* __restrict__ Wo,     // (256, 256) f16
    const float* __restrict__ b_out,
    float* __restrict__ out)             // (LQ, 256) f32
{
  const int t  = threadIdx.x;
  const int ql = t >> 4;
  const int s  = t & 15;
  const int h  = s >> 1;
  const int hf = s & 1;
  const int q  = blockIdx.x * QPB + ql;
  const bool qok = q < LQ;
  const int qc = qok ? q : LQ - 1;

  __shared__ float s_off[QPB][128];
  __shared__ float s_w[QPB][64];
  __shared__ float s_ref[QPB][48];
  __shared__ unsigned char s_vm[QPB];
  __shared__ float s_ic[QPB];
  __shared__ _Float16 s_slot[QPB][SLOT_LD];

  {
    const half8 o8 = *(const half8*)(offb + (size_t)qc * 128 + s * 8);
#pragma unroll
    for (int k = 0; k < 8; ++k) s_off[ql][s * 8 + k] = (float)o8[k];
    const f32x4 w4 = *(const f32x4*)(wbuf + (size_t)qc * 64 + s * 4);
#pragma unroll
    for (int k = 0; k < 4; ++k) s_w[ql][s * 4 + k] = w4[k];
#pragma unroll
    for (int rep = 0; rep < 3; ++rep) {
      const int k = s + rep * 16;
      s_ref[ql][k] = ref[((size_t)(k >> 3) * LQ + qc) * 8 + (k & 7)];
    }
    if (s == 0) {
      s_vm[ql] = qok ? vm[q] : (unsigned char)0;
      s_ic[ql] = qok ? invc[q] : 1.f;
    }
  }
  __syncthreads();

  // hoist this head's weights + offsets to registers (once)
  float w8[8], ox[8], oy[8];
#pragma unroll
  for (int p = 0; p < 8; ++p) {
    w8[p] = s_w[ql][h * 8 + p];
    ox[p] = s_off[ql][(h * 8 + p) * 2 + 0];
    oy[p] = s_off[ql][(h * 8 + p) * 2 + 1];
  }

  float acc[16];
#pragma unroll
  for (int i = 0; i < 16; ++i) acc[i] = 0.f;

  const int chbase = h * 32 + hf * 16;
  const unsigned vmq = s_vm[ql];

  for (int cam = 0; cam < NCAMS; ++cam) {
    if (!((vmq >> cam) & 1)) continue;  // exec-masked: no loads for invisible
    const _Float16* vpc = vp + (size_t)cam * (S_TOT * CDIM) + chbase;
#pragma unroll
    for (int p = 0; p < 8; ++p) {
      const int z = p & 3;
      const float lx = s_ref[ql][cam * 8 + z * 2 + 0] + ox[p];
      const float ly = s_ref[ql][cam * 8 + z * 2 + 1] + oy[p];
      const float x = lx * 100.f - 0.5f;
      const float y = ly * 58.f - 0.5f;
      const float x0f = floorf(x), y0f = floorf(y);
      const float fx = x - x0f, fy = y - y0f;
      const int x0 = (int)x0f, y0 = (int)y0f;
      const float wgt = w8[p];
      const float w00 = (1.f - fy) * (1.f - fx) * wgt;
      const float w01 = (1.f - fy) * fx * wgt;
      const float w10 = fy * (1.f - fx) * wgt;
      const float w11 = fy * fx * wgt;
      const bool xv0 = (x0 >= 0) && (x0 < SPA_W);
      const bool xv1 = (x0 + 1 >= 0) && (x0 + 1 < SPA_W);
#pragma unroll
      for (int dy = 0; dy < 2; ++dy) {
        const int yy = y0 + dy;
        if (yy < 0 || yy >= SPA_H) continue;
        const _Float16* rowp = vpc + (size_t)(yy * SPA_W) * CDIM;
        const float wl = dy ? w10 : w00;
        const float wr = dy ? w11 : w01;
        if (xv0) {
          const _Float16* tp = rowp + (size_t)x0 * CDIM;
          half8 v0 = *(const half8*)tp;
          half8 v1 = *(const half8*)(tp + 8);
#pragma unroll
          for (int i = 0; i < 8; ++i) acc[i]     = fmaf(wl, (float)v0[i], acc[i]);
#pragma unroll
          for (int i = 0; i < 8; ++i) acc[8 + i] = fmaf(wl, (float)v1[i], acc[8 + i]);
        }
        if (xv1) {
          const _Float16* tp = rowp + (size_t)(x0 + 1) * CDIM;
          half8 v0 = *(const half8*)tp;
          half8 v1 = *(const half8*)(tp + 8);
#pragma unroll
          for (int i = 0; i < 8; ++i) acc[i]     = fmaf(wr, (float)v0[i], acc[i]);
#pragma unroll
          for (int i = 0; i < 8; ++i) acc[8 + i] = fmaf(wr, (float)v1[i], acc[8 + i]);
        }
      }
    }
  }

  // phase boundary: slots (invc folded, f16) -> LDS
  {
    const float sc = s_ic[ql];
    half8 o0, o1;
#pragma unroll
    for (int i = 0; i < 8; ++i) {
      o0[i] = (_Float16)(acc[i] * sc);
      o1[i] = (_Float16)(acc[8 + i] * sc);
    }
    *(half8*)&s_slot[ql][chbase] = o0;
    *(half8*)&s_slot[ql][chbase + 8] = o1;
  }
  __syncthreads();

  // phase 2: 16 x 256 x 256 GEMM.  Wave w -> cols [w*64, w*64+64), NT=4.
  const int lane = t & 63;
  const int wave = t >> 6;
  const int m15  = lane & 15;
  const int quad = lane >> 4;
  const int colbase = wave * 64;

  const _Float16* wrow[4];
  float bvv[4];
#pragma unroll
  for (int tt = 0; tt < 4; ++tt) {
    const int c = colbase + tt * 16 + m15;
    wrow[tt] = Wo + (size_t)c * CDIM;
    bvv[tt] = b_out[c];
  }

  f32x4 oacc[4];
#pragma unroll
  for (int tt = 0; tt < 4; ++tt) oacc[tt] = (f32x4){0.f, 0.f, 0.f, 0.f};

#pragma unroll
  for (int kk = 0; kk < CDIM; kk += 32) {
    const int ko = kk + quad * 8;
    const half8 a = *(const half8*)&s_slot[m15][ko];
    half8 b[4];
#pragma unroll
    for (int tt = 0; tt < 4; ++tt) b[tt] = *(const half8*)(wrow[tt] + ko);
#pragma unroll
    for (int tt = 0; tt < 4; ++tt)
      oacc[tt] = __builtin_amdgcn_mfma_f32_16x16x32_f16(a, b[tt], oacc[tt], 0, 0, 0);
  }

#pragma unroll
  for (int tt = 0; tt < 4; ++tt) {
    const int col = colbase + tt * 16 + m15;
#pragma unroll
    for (int i = 0; i < 4; ++i) {
      const int r = blockIdx.x * QPB + quad * 4 + i;
      if (r < LQ) out[(size_t)r * CDIM + col] = oacc[tt][i] + bvv[tt];
    }
  }
}

extern "C" void kernel_launch(void* const* d_in, const int* in_sizes, int n_in,
                              void* d_out, int out_size, void* d_ws, size_t ws_size,
                              hipStream_t stream) {
  const float* query  = (const float*)d_in[0];
  const float* refpts = (const float*)d_in[1];
  const int*   bev    = (const int*)d_in[2];
  const float* value  = (const float*)d_in[3];
  const float* W_off  = (const float*)d_in[4];
  const float* b_off  = (const float*)d_in[5];
  const float* W_attn = (const float*)d_in[6];
  const float* b_attn = (const float*)d_in[7];
  const float* W_val  = (const float*)d_in[8];
  const float* b_val  = (const float*)d_in[9];
  const float* W_out  = (const float*)d_in[10];
  const float* b_out  = (const float*)d_in[11];

  char* ws = (char*)d_ws;
  _Float16*      vp    = (_Float16*)(ws + 0);          // 17,817,600
  _Float16*      offb  = (_Float16*)(ws + 17817600);   //  5,760,000
  float*         wbuf  = (float*)   (ws + 23577600);   //  5,760,000
  unsigned char* vm    = (unsigned char*)(ws + 29337600); // 22,528 (padded)
  float*         invc  = (float*)   (ws + 29360128);   //     90,000
  _Float16*      Wo_h  = (_Float16*)(ws + 29450240);   //    131,072
                                                       // total: 29,581,312 B

  fused_front<<<NB_VAL + NB_Q + NB_VIS + NB_CVT, 256, 0, stream>>>(
      value, query, bev, W_val, b_val, W_off, b_off, W_attn, b_attn, W_out,
      vp, offb, wbuf, vm, invc, Wo_h);

  sampler_out<<<(LQ + QPB - 1) / QPB, 256, 0, stream>>>(
      vp, offb, wbuf, refpts, vm, invc, Wo_h, b_out, (float*)d_out);
}